// Round 13
// baseline (76189.624 us; speedup 1.0000x reference)
//
#include <hip/hip_runtime.h>
#include <hip/hip_fp16.h>

#define T_STEPS 4096
#define RES     4096
#define NIN     64
#define NOUT    32
#define NWG     256
#define TPB     512   // 8 waves; wave wv owns cols [512wv,512wv+512) of all 16 rows
#define WS2     4104  // halfs per W row in LDS (4096 + 8 pad)
#define NSLOT   8     // per-XCD broadcast ring depth

typedef unsigned long long ull;
typedef _Float16 half8 __attribute__((ext_vector_type(8)));
typedef float    f32x4 __attribute__((ext_vector_type(4)));

// hwreg(HW_REG_XCC_ID=20, offset 0, size 32)
#define XCC_HWREG ((31 << 11) | 20)

// all 4 encoded halfs nonzero? (published x+2 in (1,3): never 0x0000)
__device__ __forceinline__ bool ok4(ull q) {
    return ((unsigned short)q) && ((unsigned short)(q >> 16)) &&
           ((unsigned short)(q >> 32)) && ((unsigned short)(q >> 48));
}

// L1-bypassing, L2-served load (XCD-coherent with plain stores from same XCD)
__device__ __forceinline__ ull ld_sc0(const ull* p) {
    ull r;
    asm volatile("global_load_dwordx2 %0, %1, off sc0\n\t"
                 "s_waitcnt vmcnt(0)"
                 : "=v"(r) : "v"(p) : "memory");
    return r;
}

__global__ void esn_init(unsigned short* __restrict__ Xh) {
    int i = blockIdx.x * 256 + threadIdx.x;
    if (i < RES) Xh[i] = 0x4000;               // half(2.0) == encoded x[0] = 0
}

// ---------------------------------------------------------------------------
// Persistent recurrence. 256 WGs x 512 thr; WG g owns rows 16g..16g+15.
// W in LDS fp16, LAUNDERED staging (r12: kills the global-remat restream).
// MFMA scheme unchanged (HW-validated r9/r11/r12, absmax == f32 rounds).
//
// ROUND-12 POST-MORTEM: all-WG global polling self-congests the coherence
// fabric (~2 MB per sweep-round chip-wide); idle waves re-sweep more ->
// 5 us/step equilibrium. FIX: hierarchical exchange.
//   - leader WG per PHYSICAL XCD (s_getreg(XCC_ID) + atomic rank election)
//     polls the global row (sc1 atomics) and re-publishes each ready 8-B
//     chunk into a per-XCD ring slot with PLAIN stores (land in shared L2).
//   - sibling WGs poll the ring with sc0 loads (L1-bypass, L2-served):
//     ZERO fabric traffic, ~300 cyc rounds, s_sleep(1) backoff.
//   - per-chunk global RESCUE after 48 failed local tries: correct and
//     deadlock-free even if XCD grouping is wrong (worst case ~ r12 perf).
//   - leader zeroes slot (t+5)&7 each step (6-step margin vs <=1-step lag).
// U inline: u-dot = shfl-reduce(win*inp[t]) computed before the poll (hidden).
// ---------------------------------------------------------------------------
__global__ __launch_bounds__(TPB, 2)
void esn_recur(const float* __restrict__ inp,
               const float* __restrict__ Win,
               const float* __restrict__ W,
               __half* __restrict__ xb,          // [8 xcd][NSLOT][RES] ring
               int*    __restrict__ ranks,       // [8] rank counters (zeroed)
               unsigned short* __restrict__ Xh)  // [T][RES] fp16 encoded
{
    __shared__ __align__(16) __half Wl[16 * WS2];  // 128.25 KiB fp16 W tile
    __shared__ __align__(16) __half xh[RES];       // 8 KiB wave-private slices
    __shared__ float red[2][16][9];                // padded partials, parity dbuf
    __shared__ int   s_meta[2];                    // xcd, rank

    const int g    = blockIdx.x;
    const int tid  = threadIdx.x;
    const int wv   = tid >> 6;
    const int lane = tid & 63;
    const int q    = lane >> 4;      // k-subgroup 0..3 (8 k's each)
    const int r    = lane & 15;      // A row within the 16-row tile

    // ---- leader election on the PHYSICAL XCD --------------------------------
    if (tid == 0) {
        int xcd = (int)(__builtin_amdgcn_s_getreg(XCC_HWREG) & 7u);
        s_meta[0] = xcd;
        s_meta[1] = atomicAdd(&ranks[xcd], 1);
    }

    // ---- stage W -> LDS fp16, LAUNDERED (once; coalesced 256 KB per WG) ---
    {
        const float4* Wg = (const float4*)(W + (size_t)g * 16 * RES);
        for (int idx = tid; idx < 16 * RES / 4; idx += TPB) {
            float4 v  = Wg[idx];
            int  row  = idx >> 10;
            int  c    = (idx & 1023) * 4;
            __half h0 = __float2half_rn(v.x), h1 = __float2half_rn(v.y);
            __half h2 = __float2half_rn(v.z), h3 = __float2half_rn(v.w);
            uint2 pk;
            pk.x = (unsigned)__half_as_ushort(h0) | ((unsigned)__half_as_ushort(h1) << 16);
            pk.y = (unsigned)__half_as_ushort(h2) | ((unsigned)__half_as_ushort(h3) << 16);
            asm volatile("" : "+v"(pk.x), "+v"(pk.y));   // no pure provenance
            *(uint2*)&Wl[row * WS2 + c] = pk;
        }
    }
    __syncthreads();                               // W tile + s_meta ready

    const int  xcd  = s_meta[0];
    const bool lead = (s_meta[1] == 0);
    __half* xbL = xb + (size_t)xcd * NSLOT * RES;  // my XCD's ring

    // ---- A-fragments from laundered LDS (no remat source exists) ----------
    half8 wA[16];
    {
        const half8* wrow = (const half8*)(Wl + r * WS2 + 512 * wv + 8 * q);
#pragma unroll
        for (int c = 0; c < 16; ++c) wA[c] = wrow[4 * c];
    }
    // ---- C-init = -2 * rowsum(W slice) via ones-MFMA (same layout path) ---
    f32x4 nrs;
    {
        half8 ones;
#pragma unroll
        for (int j = 0; j < 8; ++j) ones[j] = (_Float16)1.0f;
        f32x4 s0 = {0.f, 0.f, 0.f, 0.f}, s1 = {0.f, 0.f, 0.f, 0.f};
#pragma unroll
        for (int c = 0; c < 16; c += 2) {
            s0 = __builtin_amdgcn_mfma_f32_16x16x32_f16(wA[c],     ones, s0, 0, 0, 0);
            s1 = __builtin_amdgcn_mfma_f32_16x16x32_f16(wA[c + 1], ones, s1, 0, 0, 0);
        }
        nrs = (s0 + s1) * (-2.0f);
    }

    // W_in rows for this wave's two published rows (64 cols == wave width)
    const float win0 = Win[(size_t)(16 * g + 2 * wv)     * NIN + lane];
    const float win1 = Win[(size_t)(16 * g + 2 * wv + 1) * NIN + lane];

    for (int t = 1; t < T_STEPS; ++t) {
        // ---- u-dot for my 2 rows, computed pre-poll (hidden under wait) ----
        float ut = inp[(size_t)t * NIN + lane];
        float u0 = win0 * ut, u1 = win1 * ut;
#pragma unroll
        for (int off = 32; off > 0; off >>= 1) {
            u0 += __shfl_xor(u0, off, 64);
            u1 += __shfl_xor(u1, off, 64);
        }

        // ---- obtain my wave's 16 B of x[t-1] -------------------------------
        const int  slot = (t - 1) & (NSLOT - 1);
        const ull* gsrc = (const ull*)(Xh + (size_t)(t - 1) * RES) + 128 * wv + 2 * lane;
        ull*       lrow = (ull*)(xbL + (size_t)slot * RES) + 128 * wv + 2 * lane;

        ull q0 = 0, q1 = 0;
        int need = 3;
        if (lead) {
            // leader: poll global (sc1), re-publish chunks to the XCD ring
            do {
                if (need & 1) { q0 = __hip_atomic_load(gsrc,     __ATOMIC_RELAXED, __HIP_MEMORY_SCOPE_AGENT); if (ok4(q0)) { lrow[0] = q0; need &= ~1; } }
                if (need & 2) { q1 = __hip_atomic_load(gsrc + 1, __ATOMIC_RELAXED, __HIP_MEMORY_SCOPE_AGENT); if (ok4(q1)) { lrow[1] = q1; need &= ~2; } }
            } while (need);
            // pre-zero the slot that will hold row t+5 (6-step reuse margin)
            ((uint4*)(xbL + (size_t)((t + 5) & (NSLOT - 1)) * RES))[tid] =
                make_uint4(0u, 0u, 0u, 0u);
        } else {
            // sibling: poll the XCD-local copy (L2-served, zero fabric)
            int tries = 0;
            do {
                if (need & 1) { q0 = ld_sc0(lrow);     if (ok4(q0)) need &= ~1; }
                if (need & 2) { q1 = ld_sc0(lrow + 1); if (ok4(q1)) need &= ~2; }
                if (need) {
                    __builtin_amdgcn_s_sleep(1);
                    if (++tries > 48) {   // rescue: authoritative global copy
                        if (need & 1) { q0 = __hip_atomic_load(gsrc,     __ATOMIC_RELAXED, __HIP_MEMORY_SCOPE_AGENT); if (ok4(q0)) need &= ~1; }
                        if (need & 2) { q1 = __hip_atomic_load(gsrc + 1, __ATOMIC_RELAXED, __HIP_MEMORY_SCOPE_AGENT); if (ok4(q1)) need &= ~2; }
                    }
                }
            } while (need);
        }

        // ---- bounce raw encoded slice through LDS (wave-private) ----------
        uint4 sv;
        sv.x = (unsigned)q0; sv.y = (unsigned)(q0 >> 32);
        sv.z = (unsigned)q1; sv.w = (unsigned)(q1 >> 32);
        *(uint4*)(xh + 512 * wv + 8 * lane) = sv;
        asm volatile("s_waitcnt lgkmcnt(0)" ::: "memory");

        // ---- 16 MFMAs: C = -2*rowsum + A(W) * B(x^) -----------------------
        const half8* xbp = (const half8*)(xh + 512 * wv);
        f32x4 acc0 = nrs;
        f32x4 acc1 = {0.f, 0.f, 0.f, 0.f};
#pragma unroll
        for (int c = 0; c < 16; c += 2) {
            acc0 = __builtin_amdgcn_mfma_f32_16x16x32_f16(wA[c],     xbp[4 * c + q],       acc0, 0, 0, 0);
            acc1 = __builtin_amdgcn_mfma_f32_16x16x32_f16(wA[c + 1], xbp[4 * (c + 1) + q], acc1, 0, 0, 0);
        }
        f32x4 acc = acc0 + acc1;

        // ---- C col 0 lanes publish partials (rows 4q..4q+3) ---------------
        if ((lane & 15) == 0) {
#pragma unroll
            for (int i = 0; i < 4; ++i)
                red[t & 1][4 * q + i][wv] = acc[i];
        }
        __syncthreads();                     // the ONE barrier per step

        // ---- wave wv reduces rows 2wv, 2wv+1; adds u; publishes global ----
        {
            const int row = 2 * wv + ((lane >> 3) & 1);
            float s = red[t & 1][row][lane & 7];
            s += __shfl_xor(s, 1, 64);
            s += __shfl_xor(s, 2, 64);
            s += __shfl_xor(s, 4, 64);       // lanes 0,8: row sums
            float s2 = __shfl_xor(s, 8, 64); // lane 0 <- row 2wv+1 sum
            if (lane == 0) {
                float x0 = tanhf(s + u0), x1 = tanhf(s2 + u1);
                unsigned e0 = (unsigned)__half_as_ushort(__float2half_rn(x0 + 2.0f));
                unsigned e1 = (unsigned)__half_as_ushort(__float2half_rn(x1 + 2.0f));
                __hip_atomic_store((unsigned*)(Xh + (size_t)t * RES + 16 * g) + wv,
                                   e0 | (e1 << 16),
                                   __ATOMIC_RELAXED, __HIP_MEMORY_SCOPE_AGENT);
            }
        }
    }
}

// ---------------------------------------------------------------------------
// Readout: out[T,32] = decode(Xh) @ W_out. 2 t-rows/block.
// ---------------------------------------------------------------------------
__global__ __launch_bounds__(256)
void esn_out(const unsigned short* __restrict__ Xh,
             const float* __restrict__ Wout,
             float* __restrict__ out)
{
    __shared__ float xs[2 * RES];
    __shared__ float red[2][8][32];
    const int tid = threadIdx.x;
    const int t0  = blockIdx.x * 2;

    const uint4* s4 = (const uint4*)(Xh + (size_t)t0 * RES);
    for (int i = tid; i < 2 * RES / 8; i += 256) {
        uint4 v  = s4[i];
        float* d = &xs[8 * i];
        float2 f;
        f = __half22float2(*(__half2*)&v.x); d[0] = f.x - 2.f; d[1] = f.y - 2.f;
        f = __half22float2(*(__half2*)&v.y); d[2] = f.x - 2.f; d[3] = f.y - 2.f;
        f = __half22float2(*(__half2*)&v.z); d[4] = f.x - 2.f; d[5] = f.y - 2.f;
        f = __half22float2(*(__half2*)&v.w); d[6] = f.x - 2.f; d[7] = f.y - 2.f;
    }
    __syncthreads();

    const int o  = tid & 31;
    const int sg = tid >> 5;
    float acc0 = 0.f, acc1 = 0.f;
    const int rbeg = sg * 512;
    for (int rr = rbeg; rr < rbeg + 512; ++rr) {
        float wv = Wout[(size_t)rr * NOUT + o];
        acc0 += xs[rr] * wv;
        acc1 += xs[RES + rr] * wv;
    }
    red[0][sg][o] = acc0;
    red[1][sg][o] = acc1;
    __syncthreads();

    if (tid < 64) {
        const int h = tid >> 5, oo = tid & 31;
        float s = 0.f;
#pragma unroll
        for (int k = 0; k < 8; ++k) s += red[h][k][oo];
        out[(size_t)(t0 + h) * NOUT + oo] = s;
    }
}

// ---------------------------------------------------------------------------
extern "C" void kernel_launch(void* const* d_in, const int* in_sizes, int n_in,
                              void* d_out, int out_size, void* d_ws, size_t ws_size,
                              hipStream_t stream)
{
    const float* inputs = (const float*)d_in[0];   // [T, 64]
    const float* W_in   = (const float*)d_in[1];   // [RES, 64]
    const float* W      = (const float*)d_in[2];   // [RES, RES]
    const float* W_out  = (const float*)d_in[3];   // [RES, 32]
    float* out = (float*)d_out;                    // [T, 32]

    char* ws = (char*)d_ws;
    unsigned short* Xh = (unsigned short*)ws;                       // 32 MiB
    __half* xb  = (__half*)(ws + (size_t)T_STEPS * RES * 2);        // 512 KiB ring
    int*    rk  = (int*)(ws + (size_t)T_STEPS * RES * 2 + 8 * NSLOT * RES * 2);

    // Replay-safe: zero history (0x0000 = "not written"), re-encode row 0,
    // zero the broadcast ring and the rank counters.
    hipMemsetAsync(Xh, 0, (size_t)T_STEPS * RES * sizeof(unsigned short), stream);
    hipMemsetAsync(xb, 0, (size_t)8 * NSLOT * RES * sizeof(__half), stream);
    hipMemsetAsync(rk, 0, 64, stream);
    esn_init<<<dim3((RES + 255) / 256), dim3(256), 0, stream>>>(Xh);

    esn_recur<<<dim3(NWG), dim3(TPB), 0, stream>>>(inputs, W_in, W, xb, rk, Xh);
    esn_out<<<dim3(T_STEPS / 2), dim3(256), 0, stream>>>(Xh, W_out, out);
}

// Round 15
// 24887.091 us; speedup vs baseline: 3.0614x; 3.0614x over previous
//
#include <hip/hip_runtime.h>
#include <hip/hip_fp16.h>

#define T_STEPS 4096
#define RES     4096
#define NIN     64
#define NOUT    32
#define NWG     256
#define TPB     512           // 8 waves; wave wv owns cols [512wv,512wv+512)
#define WSH     4104          // halfs per W row in LDS (4096 + 8 pad)
#define WRU     (WSH / 8)     // 513 uint4 per row

typedef unsigned long long ull;
typedef _Float16 hv2 __attribute__((ext_vector_type(2)));

__device__ __forceinline__ float dot8(uint4 wq, uint4 xq, float acc) {
    acc = __builtin_amdgcn_fdot2(__builtin_bit_cast(hv2, wq.x), __builtin_bit_cast(hv2, xq.x), acc, false);
    acc = __builtin_amdgcn_fdot2(__builtin_bit_cast(hv2, wq.y), __builtin_bit_cast(hv2, xq.y), acc, false);
    acc = __builtin_amdgcn_fdot2(__builtin_bit_cast(hv2, wq.z), __builtin_bit_cast(hv2, xq.z), acc, false);
    acc = __builtin_amdgcn_fdot2(__builtin_bit_cast(hv2, wq.w), __builtin_bit_cast(hv2, xq.w), acc, false);
    return acc;
}

// all 4 encoded halfs nonzero? (published x+2 in (1,3): never 0x0000)
__device__ __forceinline__ bool ok4(ull q) {
    return ((unsigned short)q) && ((unsigned short)(q >> 16)) &&
           ((unsigned short)(q >> 32)) && ((unsigned short)(q >> 48));
}

// packed fp16 pair: (enc - 2.0) exactly — THE r14 BUG was dropping this:
// dot2 scheme has no rowsum compensation, x must be DECODED at staging.
__device__ __forceinline__ unsigned sub2(unsigned u) {
    __half2 h = *(__half2*)&u;
    __half2 r = __hsub2(h, __floats2half2_rn(2.f, 2.f));
    return *(unsigned*)&r;
}

__global__ void esn_init(unsigned short* __restrict__ Xh) {
    int i = blockIdx.x * 256 + threadIdx.x;
    if (i < RES) Xh[i] = 0x4000;               // half(2.0) == encoded x[0] = 0
}

// U = inputs @ W_in^T as fp16. Block: 16 t x 256 j. Grid (16, 256).
__global__ __launch_bounds__(256)
void esn_uproj(const float* __restrict__ inp, const float* __restrict__ Win,
               __half* __restrict__ Uh)
{
    __shared__ float us[16][NIN];
    const int tid = threadIdx.x;
    const int j   = blockIdx.x * 256 + tid;
    const int t0  = blockIdx.y * 16;
    ((float4*)us)[tid] = ((const float4*)(inp + (size_t)t0 * NIN))[tid];
    float wr[NIN];
    const float4* wp = (const float4*)(Win + (size_t)j * NIN);
#pragma unroll
    for (int k = 0; k < 16; ++k) {
        float4 v = wp[k];
        wr[4*k] = v.x; wr[4*k+1] = v.y; wr[4*k+2] = v.z; wr[4*k+3] = v.w;
    }
    __syncthreads();
#pragma unroll
    for (int tt = 0; tt < 16; ++tt) {
        float s = 0.f;
#pragma unroll
        for (int k = 0; k < NIN; ++k) s += wr[k] * us[tt][k];
        Uh[(size_t)(t0 + tt) * RES + j] = __float2half_rn(s);
    }
}

// ---------------------------------------------------------------------------
// Persistent recurrence — round-8 base (best: 11.86 ms) + CHUNKED ARRIVAL-
// DRIVEN COMPUTE (r14, fixed). 256 WGs x 512 thr; WG g owns rows 16g..16g+15;
// wave wv owns cols [512wv,+512) split into 64 16-B units (one per lane).
//
// r8's step = wait-for-ALL-units (~1.2us, jittered producers) THEN compute
// (~1.3us LDS-bound). Overlap them: each lane polls its own unit (r8's
// addresses); arrived units are DECODED (sub2 — r14's missing piece) and
// staged to LDS; a wave __ballot mask lets every lane immediately dot the
// (W,x) chunk pairs that just became ready (ctz loop). Exit wave-uniform.
//
// u_t: precomputed Uh added at the reduce tail (proven r12/r13).
// W staging LAUNDERED (r12, anti-forwarding). Publish/poll/reduce: r8.
// ---------------------------------------------------------------------------
__global__ __launch_bounds__(TPB, 1)
void esn_recur(const __half* __restrict__ Uh,
               const float* __restrict__ W,
               unsigned short* __restrict__ Xh)   // [T][RES] fp16 encoded
{
    __shared__ __align__(16) __half Wl[16 * WSH];  // 128.25 KiB fp16 W tile
    __shared__ __align__(16) __half xh[RES];       // 8 KiB wave-private slices
    __shared__ float red[2][16][33];               // partials, parity dbuf

    const int g    = blockIdx.x;
    const int tid  = threadIdx.x;
    const int wv   = tid >> 6;
    const int lane = tid & 63;
    const int r    = lane & 15;      // row within the 16-row tile
    const int cg   = lane >> 4;      // column group 0..3 (16 units each)

    // ---- stage W -> LDS fp16, LAUNDERED (once; coalesced 256 KB per WG) ---
    {
        const float4* Wg = (const float4*)(W + (size_t)g * 16 * RES);
        for (int idx = tid; idx < 16 * RES / 4; idx += TPB) {
            float4 v  = Wg[idx];
            int  row  = idx >> 10;
            int  c    = (idx & 1023) * 4;
            __half h0 = __float2half_rn(v.x), h1 = __float2half_rn(v.y);
            __half h2 = __float2half_rn(v.z), h3 = __float2half_rn(v.w);
            uint2 pk;
            pk.x = (unsigned)__half_as_ushort(h0) | ((unsigned)__half_as_ushort(h1) << 16);
            pk.y = (unsigned)__half_as_ushort(h2) | ((unsigned)__half_as_ushort(h3) << 16);
            asm volatile("" : "+v"(pk.x), "+v"(pk.y));   // no pure provenance
            *(uint2*)&Wl[row * WSH + c] = pk;
        }
    }
    __syncthreads();                               // W tile ready

    const uint4* WQ   = (const uint4*)Wl;
    const uint4* XQ   = (const uint4*)xh;
    const int    wrow = r * WRU + wv * 64;         // + unit
    const int    xrow = wv * 64;                   // + unit

    for (int t = 1; t < T_STEPS; ++t) {
        // ---- prefetch U[t] for my wave's 2 rows (hides under poll) --------
        const __half2 u2 = *(const __half2*)(Uh + (size_t)t * RES + 16 * g + 2 * wv);

        // ---- chunked poll + decode + stage + arrival-driven dot -----------
        const ull* src = (const ull*)(Xh + (size_t)(t - 1) * RES) + 128 * wv + 2 * lane;
        ull q0 = 0, q1 = 0;
        int  need   = 3;
        bool staged = false;
        float acc   = 0.f;
        unsigned done = 0;
        for (;;) {
            if (!staged) {
                if (need & 1) { q0 = __hip_atomic_load(src,     __ATOMIC_RELAXED, __HIP_MEMORY_SCOPE_AGENT); if (ok4(q0)) need &= ~1; }
                if (need & 2) { q1 = __hip_atomic_load(src + 1, __ATOMIC_RELAXED, __HIP_MEMORY_SCOPE_AGENT); if (ok4(q1)) need &= ~2; }
                if (!need) {
                    uint4 sv;                       // DECODE at staging (r8)
                    sv.x = sub2((unsigned)q0); sv.y = sub2((unsigned)(q0 >> 32));
                    sv.z = sub2((unsigned)q1); sv.w = sub2((unsigned)(q1 >> 32));
                    *(uint4*)(xh + 512 * wv + 8 * lane) = sv;   // unit `lane`
                    staged = true;
                }
            }
            asm volatile("s_waitcnt lgkmcnt(0)" ::: "memory");  // stages visible
            ull m = __ballot(staged);
            if (m == ~0ull) {
                // finish all remaining chunks straight-line (fast path when
                // done==0: identical to r8's 16-iteration rotated loop)
#pragma unroll
                for (int k = 0; k < 16; ++k) {
                    int b = (k + 4 * cg) & 15;
                    if (!((done >> b) & 1)) {
                        int u = 16 * cg + b;
                        acc = dot8(WQ[wrow + u], XQ[xrow + u], acc);
                    }
                }
                break;                                          // wave-uniform
            }
            unsigned m16  = (unsigned)((m >> (16 * cg)) & 0xffffu);
            unsigned todo = m16 & ~done;
            while (todo) {
                int b = __builtin_ctz(todo);
                todo &= todo - 1;
                done |= 1u << b;
                int u = 16 * cg + b;
                acc = dot8(WQ[wrow + u], XQ[xrow + u], acc);
            }
        }

        // ---- partials -> red; ONE barrier; reduce + u + publish (r8) ------
        red[t & 1][r][4 * wv + cg] = acc;
        __syncthreads();
        {
            const int row = 2 * wv + (lane >> 5);
            float s = red[t & 1][row][lane & 31];
            s += __shfl_xor(s, 1, 64);
            s += __shfl_xor(s, 2, 64);
            s += __shfl_xor(s, 4, 64);
            s += __shfl_xor(s, 8, 64);
            s += __shfl_xor(s, 16, 64);              // lanes 0,32 hold sums
            float2 uf = __half22float2(u2);
            float xn  = tanhf(s + ((lane >= 32) ? uf.y : uf.x));
            unsigned enc = (unsigned)__half_as_ushort(__float2half_rn(xn + 2.0f));
            unsigned hi  = (unsigned)__shfl((int)enc, 32, 64);
            if (lane == 0) {
                __hip_atomic_store((unsigned*)(Xh + (size_t)t * RES + 16 * g) + wv,
                                   enc | (hi << 16),
                                   __ATOMIC_RELAXED, __HIP_MEMORY_SCOPE_AGENT);
            }
        }
    }
}

// ---------------------------------------------------------------------------
// Readout: out[T,32] = decode(Xh) @ W_out. 2 t-rows/block.
// ---------------------------------------------------------------------------
__global__ __launch_bounds__(256)
void esn_out(const unsigned short* __restrict__ Xh,
             const float* __restrict__ Wout,
             float* __restrict__ out)
{
    __shared__ float xs[2 * RES];
    __shared__ float red[2][8][32];
    const int tid = threadIdx.x;
    const int t0  = blockIdx.x * 2;

    const uint4* s4 = (const uint4*)(Xh + (size_t)t0 * RES);
    for (int i = tid; i < 2 * RES / 8; i += 256) {
        uint4 v  = s4[i];
        float* d = &xs[8 * i];
        float2 f;
        f = __half22float2(*(__half2*)&v.x); d[0] = f.x - 2.f; d[1] = f.y - 2.f;
        f = __half22float2(*(__half2*)&v.y); d[2] = f.x - 2.f; d[3] = f.y - 2.f;
        f = __half22float2(*(__half2*)&v.z); d[4] = f.x - 2.f; d[5] = f.y - 2.f;
        f = __half22float2(*(__half2*)&v.w); d[6] = f.x - 2.f; d[7] = f.y - 2.f;
    }
    __syncthreads();

    const int o  = tid & 31;
    const int sg = tid >> 5;
    float acc0 = 0.f, acc1 = 0.f;
    const int rbeg = sg * 512;
    for (int rr = rbeg; rr < rbeg + 512; ++rr) {
        float wv = Wout[(size_t)rr * NOUT + o];
        acc0 += xs[rr] * wv;
        acc1 += xs[RES + rr] * wv;
    }
    red[0][sg][o] = acc0;
    red[1][sg][o] = acc1;
    __syncthreads();

    if (tid < 64) {
        const int h = tid >> 5, oo = tid & 31;
        float s = 0.f;
#pragma unroll
        for (int k = 0; k < 8; ++k) s += red[h][k][oo];
        out[(size_t)(t0 + h) * NOUT + oo] = s;
    }
}

// ---------------------------------------------------------------------------
extern "C" void kernel_launch(void* const* d_in, const int* in_sizes, int n_in,
                              void* d_out, int out_size, void* d_ws, size_t ws_size,
                              hipStream_t stream)
{
    const float* inputs = (const float*)d_in[0];   // [T, 64]
    const float* W_in   = (const float*)d_in[1];   // [RES, 64]
    const float* W      = (const float*)d_in[2];   // [RES, RES]
    const float* W_out  = (const float*)d_in[3];   // [RES, 32]
    float* out = (float*)d_out;                    // [T, 32]

    unsigned short* Xh = (unsigned short*)d_ws;    // [T][RES] fp16 encoded, 32 MiB
    __half* Uh = (__half*)((char*)d_ws + (size_t)T_STEPS * RES * 2);  // 32 MiB

    // Replay-safe: zero history (0x0000 = "not written"), re-encode row 0.
    hipMemsetAsync(Xh, 0, (size_t)T_STEPS * RES * sizeof(unsigned short), stream);
    esn_init<<<dim3((RES + 255) / 256), dim3(256), 0, stream>>>(Xh);
    esn_uproj<<<dim3(RES / 256, T_STEPS / 16), dim3(256), 0, stream>>>(inputs, W_in, Uh);

    esn_recur<<<dim3(NWG), dim3(TPB), 0, stream>>>(Uh, W, Xh);
    esn_out<<<dim3(T_STEPS / 2), dim3(256), 0, stream>>>(Xh, W_out, out);
}